// Round 7
// baseline (209.611 us; speedup 1.0000x reference)
//
#include <hip/hip_runtime.h>
#include <math.h>

#define BB 4
#define CC 256
#define DD 32
#define NN 4096

typedef __attribute__((ext_vector_type(8))) short short8;
typedef __attribute__((ext_vector_type(4))) float floatx4;
typedef __attribute__((ext_vector_type(4))) int intx4;

#define SCALEF (0.17677669529663687f * 1.4426950408889634f)  // 1/sqrt(32)*log2(e)

// float -> bf16 round-to-nearest-even
__device__ __forceinline__ ushort f2bf(float f) {
    unsigned int u = __builtin_bit_cast(unsigned int, f);
    u += 0x7FFFu + ((u >> 16) & 1u);
    return (ushort)(u >> 16);
}
// pack two floats' bf16 truncations into one dword with a single v_perm_b32
__device__ __forceinline__ int pk_trunc(float a, float b) {
    return (int)__builtin_amdgcn_perm(__builtin_bit_cast(unsigned, b),
                                      __builtin_bit_cast(unsigned, a),
                                      0x07060302u);
}
__device__ __forceinline__ float fast_exp2(float x) {
#if __has_builtin(__builtin_amdgcn_exp2f)
    return __builtin_amdgcn_exp2f(x);
#else
    return exp2f(x);
#endif
}

// ---------------------------------------------------------------------------
// Kernel 1: FUSED transpose + QKV projection.  Grid (64 n-tiles, 5 o-pairs,
// 4 b) = 1280 blocks, 256 thr.  Each block:
//   (a) stages x[b, 0:256, n0:n0+64] fp32 -> LDS bf16 tile [64n][256c]
//       (pitch 264 ushorts; prep_xt's verified pack/write math, 4 c-passes);
//   (b) wave w computes output tile mt = 2*op + (w>>1), n-half (w&1)*32:
//       A-frags converted in-register from fp32 W rows (R0-proven path),
//       B-frags = ds_read_b128 from the tile.  Outputs identical layouts to
//       the R1 qkv (qb/kb packed ushort4, vb scalar).
// Replaces prep_fused+qkv_mfma: no xT intermediate, one fewer dispatch.
// ---------------------------------------------------------------------------
#define QTP 264   // LDS pitch in ushorts (132 dwords; 132%32=4 -> 2-way max)
__global__ __launch_bounds__(256) void qkv_fused(
    const float* __restrict__ x,
    const float* __restrict__ Wq, const float* __restrict__ bq,
    const float* __restrict__ Wk, const float* __restrict__ bk,
    const float* __restrict__ Wv, const float* __restrict__ bv,
    ushort* __restrict__ qb, ushort* __restrict__ kb, ushort* __restrict__ vb)
{
    __shared__ ushort tile[64 * QTP];   // ~33 KB

    const int t = threadIdx.x;
    const int wave = t >> 6;
    const int lane = t & 63;
    const int l15 = lane & 15, qd = lane >> 4;
    const int b = blockIdx.z;
    const int n0 = blockIdx.x * 64;
    const int op = blockIdx.y;               // o-pair 0..4
    const int mt = op * 2 + (wave >> 1);     // 0..9
    const int nw = (wave & 1) * 32;          // n-half within the 64-n tile

    // ---- stage: x slice -> LDS bf16 [n][c], prep_xt math per 64-c pass ----
    {
        const int cl = (t >> 4) * 4;   // 4 c-rows per thread
        const int nl = (t & 15) * 4;   // 4 n-cols per thread
        #pragma unroll
        for (int p = 0; p < 4; ++p) {
            const int cp = p * 64;
            const float* src = x + ((size_t)b * CC + cp + cl) * NN + n0 + nl;
            floatx4 v[4];
            #pragma unroll
            for (int i = 0; i < 4; ++i) v[i] = *(const floatx4*)(src + (size_t)i * NN);
            #pragma unroll
            for (int j = 0; j < 4; ++j) {
                *(int*)&tile[(nl + j) * QTP + cp + cl]     = pk_trunc(v[0][j], v[1][j]);
                *(int*)&tile[(nl + j) * QTP + cp + cl + 2] = pk_trunc(v[2][j], v[3][j]);
            }
        }
    }
    __syncthreads();

    // ---- A-row pointers (fp32 W, converted in-register; R0-proven) ----
    const float* wr[2];
    if (mt == 0) {
        wr[0] = Wq + (size_t)l15 * CC;
        wr[1] = Wq + (size_t)(16 + l15) * CC;
    } else if (mt == 1) {
        wr[0] = Wk + (size_t)l15 * CC;
        wr[1] = Wk + (size_t)(16 + l15) * CC;
    } else {
        wr[0] = Wv + (size_t)((mt - 2) * 32 + l15) * CC;
        wr[1] = Wv + (size_t)((mt - 2) * 32 + 16 + l15) * CC;
    }

    floatx4 z = {0.f, 0.f, 0.f, 0.f};
    floatx4 acc[2][2];
    acc[0][0] = z; acc[0][1] = z; acc[1][0] = z; acc[1][1] = z;

    #pragma unroll
    for (int k0 = 0; k0 < CC; k0 += 32) {
        short8 af[2], bfr[2];
        #pragma unroll
        for (int f = 0; f < 2; ++f) {
            const float* p = wr[f] + k0 + qd * 8;
            float w[8];
            #pragma unroll
            for (int j = 0; j < 8; ++j) w[j] = p[j];
            if (mt == 0) {
                #pragma unroll
                for (int j = 0; j < 8; ++j) w[j] *= SCALEF;
            }
            intx4 d;
            d[0] = pk_trunc(w[0], w[1]); d[1] = pk_trunc(w[2], w[3]);
            d[2] = pk_trunc(w[4], w[5]); d[3] = pk_trunc(w[6], w[7]);
            af[f] = __builtin_bit_cast(short8, d);
            bfr[f] = *(const short8*)&tile[(nw + f * 16 + l15) * QTP + k0 + qd * 8];
        }
        #pragma unroll
        for (int fm = 0; fm < 2; ++fm)
            #pragma unroll
            for (int fn = 0; fn < 2; ++fn)
                acc[fm][fn] = __builtin_amdgcn_mfma_f32_16x16x32_bf16(af[fm], bfr[fn], acc[fm][fn], 0, 0, 0);
    }

    const int nb = n0 + nw;
    #pragma unroll
    for (int fm = 0; fm < 2; ++fm) {
        const int o0 = fm * 16 + qd * 4;
        if (mt == 0) {
            const floatx4 bb = *(const floatx4*)(bq + o0);
            #pragma unroll
            for (int fn = 0; fn < 2; ++fn) {
                ushort4 h;
                h.x = f2bf(acc[fm][fn][0] + bb[0] * SCALEF);
                h.y = f2bf(acc[fm][fn][1] + bb[1] * SCALEF);
                h.z = f2bf(acc[fm][fn][2] + bb[2] * SCALEF);
                h.w = f2bf(acc[fm][fn][3] + bb[3] * SCALEF);
                *(ushort4*)(qb + ((size_t)b * NN + nb + fn * 16 + l15) * DD + o0) = h;
            }
        } else if (mt == 1) {
            const floatx4 bb = *(const floatx4*)(bk + o0);
            #pragma unroll
            for (int fn = 0; fn < 2; ++fn) {
                ushort4 h;
                h.x = f2bf(acc[fm][fn][0] + bb[0]);
                h.y = f2bf(acc[fm][fn][1] + bb[1]);
                h.z = f2bf(acc[fm][fn][2] + bb[2]);
                h.w = f2bf(acc[fm][fn][3] + bb[3]);
                *(ushort4*)(kb + ((size_t)b * NN + nb + fn * 16 + l15) * DD + o0) = h;
            }
        } else {
            const int oc = (mt - 2) * 32 + o0;
            const floatx4 bb = *(const floatx4*)(bv + oc);
            #pragma unroll
            for (int r = 0; r < 4; ++r)
                #pragma unroll
                for (int fn = 0; fn < 2; ++fn)
                    vb[((size_t)b * CC + oc + r) * NN + nb + fn * 16 + l15] = f2bf(acc[fm][fn][r] + bb[r]);
        }
    }
}

// ---------------------------------------------------------------------------
// Kernel 2: MFMA flash attention — R5 VERBATIM except one zero-register
// change: K(kt+1) is loaded AFTER the pt-chain and BEFORE the PV cluster
// (same kf0/kf1 registers, live range across the loop back-edge).  The PV
// cluster (~850 cy) hides the K L2 latency that R5 exposed at the top of
// every iteration.  V load placement, all index math, epilogue: unchanged.
// ---------------------------------------------------------------------------
__global__ __launch_bounds__(256, 2) void attn_mfma(
    const ushort* __restrict__ qb, const ushort* __restrict__ kb,
    const ushort* __restrict__ vb, ushort* __restrict__ aoT)
{
    __shared__ float red[2][8192];   // [slot][((f*8+ct)*4+r)*64 + lane]
    __shared__ float lred[2][64];    // [slot][f*16 + q]

    const int t = threadIdx.x;
    const int kh = t >> 6;               // key-quarter 0..3
    const int lane = t & 63;
    const int l15 = lane & 15;
    const int qd = lane >> 4;
    const int slot = blockIdx.x;         // ~XCD id (round-robin heuristic)
    const int b = slot >> 1;             // 2 XCDs per batch
    const int qt = (slot & 1) * 32 + blockIdx.y;
    const int q0 = qt * 64;
    const int c0 = blockIdx.z * 128;

    const ushort* krow = kb + ((size_t)b * NN + kh * 1024 + l15) * DD + qd * 8;
    const ushort* vrow = vb + ((size_t)b * CC + c0 + l15) * (size_t)NN + kh * 1024 + qd * 8;

    short8 qf[4];
    #pragma unroll
    for (int f = 0; f < 4; ++f)
        qf[f] = *(const short8*)(qb + ((size_t)b * NN + q0 + f * 16 + l15) * DD + qd * 8);

    const short8 ones = {0x3F80, 0x3F80, 0x3F80, 0x3F80, 0x3F80, 0x3F80, 0x3F80, 0x3F80};

    floatx4 z = {0.f, 0.f, 0.f, 0.f};
    floatx4 acc[4][8];   // [qfrag][chfrag]
    floatx4 accl[4];
    #pragma unroll
    for (int f = 0; f < 4; ++f) {
        accl[f] = z;
        #pragma unroll
        for (int c = 0; c < 8; ++c) acc[f][c] = z;
    }

    const int base  = (qd & 1) * 32 + l15;   // proven transpose lane mapping
    const int base2 = base + 16;
    const bool hi = (lane >= 32);

    // K(0) loaded up front; thereafter K(kt+1) is prefetched under PV(kt).
    short8 kf0 = *(const short8*)(krow);
    short8 kf1 = *(const short8*)(krow + 16 * DD);

    for (int kt = 0; kt < 32; ++kt) {
        short8 vf[8];
        #pragma unroll
        for (int ct = 0; ct < 8; ++ct)
            vf[ct] = *(const short8*)(vrow + (size_t)ct * 16 * NN);
        vrow += 32;

        short8 pt[4];
        #pragma unroll
        for (int f = 0; f < 4; ++f) {
            floatx4 s0 = __builtin_amdgcn_mfma_f32_16x16x32_bf16(kf0, qf[f], z, 0, 0, 0);
            floatx4 s1 = __builtin_amdgcn_mfma_f32_16x16x32_bf16(kf1, qf[f], z, 0, 0, 0);

            float e00 = fast_exp2(s0[0]), e01 = fast_exp2(s0[1]);
            float e02 = fast_exp2(s0[2]), e03 = fast_exp2(s0[3]);
            float e10 = fast_exp2(s1[0]), e11 = fast_exp2(s1[1]);
            float e12 = fast_exp2(s1[2]), e13 = fast_exp2(s1[3]);

            int A0 = pk_trunc(e00, e01);
            int A1 = pk_trunc(e02, e03);
            int B0 = pk_trunc(e10, e11);
            int B1 = pk_trunc(e12, e13);

            int w0a = __shfl(A0, base);  int w0b = __shfl(B0, base);
            int w1a = __shfl(A1, base);  int w1b = __shfl(B1, base);
            int w2a = __shfl(A0, base2); int w2b = __shfl(B0, base2);
            int w3a = __shfl(A1, base2); int w3b = __shfl(B1, base2);

            intx4 ptd;
            ptd[0] = hi ? w0b : w0a;
            ptd[1] = hi ? w1b : w1a;
            ptd[2] = hi ? w2b : w2a;
            ptd[3] = hi ? w3b : w3a;
            pt[f] = __builtin_bit_cast(short8, ptd);
        }

        // ---- prefetch K(kt+1) into the SAME registers (zero reg growth);
        //      latency hidden under the ones+PV MFMA cluster below ----
        krow += 32 * DD;
        if (kt < 31) {
            kf0 = *(const short8*)(krow);
            kf1 = *(const short8*)(krow + 16 * DD);
        }

        #pragma unroll
        for (int f = 0; f < 4; ++f)
            accl[f] = __builtin_amdgcn_mfma_f32_16x16x32_bf16(ones, pt[f], accl[f], 0, 0, 0);

        __builtin_amdgcn_s_setprio(1);
        #pragma unroll
        for (int ct = 0; ct < 8; ++ct)
            #pragma unroll
            for (int f = 0; f < 4; ++f)
                acc[f][ct] = __builtin_amdgcn_mfma_f32_16x16x32_bf16(vf[ct], pt[f], acc[f][ct], 0, 0, 0);
        __builtin_amdgcn_s_setprio(0);
    }

    float lsum[4];
    #pragma unroll
    for (int f = 0; f < 4; ++f) lsum[f] = accl[f][0];

    // ---- reduction tree over key-quarters: (0+=1, 2+=3), then 0+=2 ----
    if (kh & 1) {
        const int s = kh >> 1;
        #pragma unroll
        for (int f = 0; f < 4; ++f)
            #pragma unroll
            for (int ct = 0; ct < 8; ++ct)
                #pragma unroll
                for (int r = 0; r < 4; ++r)
                    red[s][((f * 8 + ct) * 4 + r) * 64 + lane] = acc[f][ct][r];
        if (qd == 0)
            #pragma unroll
            for (int f = 0; f < 4; ++f) lred[s][f * 16 + l15] = lsum[f];
    }
    __syncthreads();
    if (!(kh & 1)) {
        const int s = kh >> 1;
        #pragma unroll
        for (int f = 0; f < 4; ++f) {
            #pragma unroll
            for (int ct = 0; ct < 8; ++ct)
                #pragma unroll
                for (int r = 0; r < 4; ++r)
                    acc[f][ct][r] += red[s][((f * 8 + ct) * 4 + r) * 64 + lane];
            lsum[f] += lred[s][f * 16 + l15];
        }
    }
    __syncthreads();
    if (kh == 2) {
        #pragma unroll
        for (int f = 0; f < 4; ++f)
            #pragma unroll
            for (int ct = 0; ct < 8; ++ct)
                #pragma unroll
                for (int r = 0; r < 4; ++r)
                    red[0][((f * 8 + ct) * 4 + r) * 64 + lane] = acc[f][ct][r];
        if (qd == 0)
            #pragma unroll
            for (int f = 0; f < 4; ++f) lred[0][f * 16 + l15] = lsum[f];
    }
    __syncthreads();
    if (kh == 0) {
        #pragma unroll
        for (int f = 0; f < 4; ++f) {
            #pragma unroll
            for (int ct = 0; ct < 8; ++ct)
                #pragma unroll
                for (int r = 0; r < 4; ++r)
                    acc[f][ct][r] += red[0][((f * 8 + ct) * 4 + r) * 64 + lane];
            lsum[f] += lred[0][f * 16 + l15];
        }
        #pragma unroll
        for (int f = 0; f < 4; ++f) {
            const float inv = 1.0f / lsum[f];
            ushort* dst = aoT + ((size_t)b * NN + q0 + f * 16 + l15) * CC + c0 + qd * 4;
            #pragma unroll
            for (int ct = 0; ct < 8; ++ct) {
                ushort4 h;
                h.x = f2bf(acc[f][ct][0] * inv);
                h.y = f2bf(acc[f][ct][1] * inv);
                h.z = f2bf(acc[f][ct][2] * inv);
                h.w = f2bf(acc[f][ct][3] * inv);
                *(ushort4*)(dst + ct * 16) = h;
            }
        }
    }
}

// ---------------------------------------------------------------------------
// Kernel 3: MFMA output projection + residual — A-frags converted from fp32
// Wp in-register (R0-proven path; removes the Wpb prep dependency).
// ---------------------------------------------------------------------------
__global__ __launch_bounds__(256) void proj_mfma(
    const ushort* __restrict__ aoT, const float* __restrict__ Wp,
    const float* __restrict__ bp, const float* __restrict__ x,
    const float* __restrict__ gamma, float* __restrict__ out)
{
    const int t = threadIdx.x;
    const int wave = t >> 6;
    const int lane = t & 63;
    const int l15 = lane & 15;
    const int qd = lane >> 4;
    const int b = blockIdx.z;
    const int m0 = blockIdx.y * 32;
    const int n0 = blockIdx.x * 128 + wave * 32;

    floatx4 z = {0.f, 0.f, 0.f, 0.f};
    floatx4 acc[2][2];   // [fm][fn]
    acc[0][0] = z; acc[0][1] = z; acc[1][0] = z; acc[1][1] = z;

    const ushort* arow = aoT + ((size_t)b * NN + n0 + l15) * CC + qd * 8;
    const float* wrow = Wp + (size_t)(m0 + l15) * CC + qd * 8;

    #pragma unroll
    for (int k0 = 0; k0 < CC; k0 += 32) {
        short8 af[2], bfr[2];
        #pragma unroll
        for (int f = 0; f < 2; ++f) {
            const float* p = wrow + (size_t)f * 16 * CC + k0;
            intx4 d;
            d[0] = pk_trunc(p[0], p[1]); d[1] = pk_trunc(p[2], p[3]);
            d[2] = pk_trunc(p[4], p[5]); d[3] = pk_trunc(p[6], p[7]);
            af[f] = __builtin_bit_cast(short8, d);
            bfr[f] = *(const short8*)(arow + (size_t)f * 16 * CC + k0);
        }
        #pragma unroll
        for (int fm = 0; fm < 2; ++fm)
            #pragma unroll
            for (int fn = 0; fn < 2; ++fn)
                acc[fm][fn] = __builtin_amdgcn_mfma_f32_16x16x32_bf16(af[fm], bfr[fn], acc[fm][fn], 0, 0, 0);
    }

    const float g = gamma[0];
    #pragma unroll
    for (int fm = 0; fm < 2; ++fm) {
        #pragma unroll
        for (int r = 0; r < 4; ++r) {
            int m = m0 + fm * 16 + qd * 4 + r;
            float bpv = bp[m];
            #pragma unroll
            for (int fn = 0; fn < 2; ++fn) {
                size_t addr = ((size_t)b * CC + m) * NN + n0 + fn * 16 + l15;
                out[addr] = fmaf(g, acc[fm][fn][r] + bpv, x[addr]);
            }
        }
    }
}

extern "C" void kernel_launch(void* const* d_in, const int* in_sizes, int n_in,
                              void* d_out, int out_size, void* d_ws, size_t ws_size,
                              hipStream_t stream)
{
    const float* x     = (const float*)d_in[0];
    const float* Wq    = (const float*)d_in[1];
    const float* bq    = (const float*)d_in[2];
    const float* Wk    = (const float*)d_in[3];
    const float* bk    = (const float*)d_in[4];
    const float* Wv    = (const float*)d_in[5];
    const float* bv    = (const float*)d_in[6];
    const float* Wp    = (const float*)d_in[7];
    const float* bp    = (const float*)d_in[8];
    const float* gamma = (const float*)d_in[9];
    float* out = (float*)d_out;

    ushort* qbw = (ushort*)d_ws;                        // B*N*32  bf16 = 1 MB
    ushort* kbw = qbw + (size_t)BB * NN * DD;           // B*N*32  bf16 = 1 MB
    ushort* vbw = kbw + (size_t)BB * NN * DD;           // B*C*N   bf16 = 8 MB
    ushort* aoT = vbw + (size_t)BB * CC * NN;           // B*N*C   bf16 = 8 MB

    qkv_fused<<<dim3(NN / 64, 5, BB), 256, 0, stream>>>(x, Wq, bq, Wk, bk, Wv, bv, qbw, kbw, vbw);
    attn_mfma<<<dim3(8, 32, 2), 256, 0, stream>>>(qbw, kbw, vbw, aoT);
    proj_mfma<<<dim3(NN / 128, CC / 32, BB), 256, 0, stream>>>(aoT, Wp, bp, x, gamma, out);
}

// Round 8
// 195.613 us; speedup vs baseline: 1.0716x; 1.0716x over previous
//
#include <hip/hip_runtime.h>
#include <math.h>

#define BB 4
#define CC 256
#define DD 32
#define NN 4096

typedef __attribute__((ext_vector_type(8))) short short8;
typedef __attribute__((ext_vector_type(4))) float floatx4;
typedef __attribute__((ext_vector_type(16))) float floatx16;
typedef __attribute__((ext_vector_type(4))) int intx4;
typedef __attribute__((ext_vector_type(2))) int intx2;

#define SCALEF (0.17677669529663687f * 1.4426950408889634f)  // 1/sqrt(32)*log2(e)

// float -> bf16 round-to-nearest-even
__device__ __forceinline__ ushort f2bf(float f) {
    unsigned int u = __builtin_bit_cast(unsigned int, f);
    u += 0x7FFFu + ((u >> 16) & 1u);
    return (ushort)(u >> 16);
}
// pack two floats' bf16 truncations into one dword with a single v_perm_b32
__device__ __forceinline__ int pk_trunc(float a, float b) {
    return (int)__builtin_amdgcn_perm(__builtin_bit_cast(unsigned, b),
                                      __builtin_bit_cast(unsigned, a),
                                      0x07060302u);
}
__device__ __forceinline__ float fast_exp2(float x) {
#if __has_builtin(__builtin_amdgcn_exp2f)
    return __builtin_amdgcn_exp2f(x);
#else
    return exp2f(x);
#endif
}
// permlane32_swap: a'.hi <- b.lo, b'.lo <- a.hi (lo/hi = 32-lane halves)
__device__ __forceinline__ void plswap(int& a, int& b) {
#if __has_builtin(__builtin_amdgcn_permlane32_swap)
    intx2 r = __builtin_amdgcn_permlane32_swap(a, b, false, false);
    a = r[0]; b = r[1];
#else
    const int lane = threadIdx.x & 63;
    const bool hi = lane >= 32;
    int a2 = __shfl(a, lane ^ 32);
    int b2 = __shfl(b, lane ^ 32);
    int na = hi ? b2 : a;
    int nb = hi ? b : a2;
    a = na; b = nb;
#endif
}

// ---------------------------------------------------------------------------
// Kernel 0: fused prep (R5-verbatim) — weight conversion (first 144 blocks)
// + x (B,C,N) fp32 -> xT (B,N,C) bf16 transpose via 64x64 LDS tile.
// ---------------------------------------------------------------------------
#define TP 66
__global__ __launch_bounds__(256) void prep_fused(
    const float* __restrict__ x,
    const float* __restrict__ Wq, const float* __restrict__ Wk,
    const float* __restrict__ Wv, const float* __restrict__ Wp,
    ushort* __restrict__ xT, ushort* __restrict__ Wall, ushort* __restrict__ Wpb)
{
    __shared__ ushort tile[64 * TP];
    const int t = threadIdx.x;

    const int bid = (blockIdx.z * gridDim.y + blockIdx.y) * gridDim.x + blockIdx.x;
    if (bid < 144) {
        const int e = (bid * 256 + t) * 4;   // 576 rows x 256 cols
        const int row = e >> 8, col = e & 255;
        const float* src;
        float s = 1.0f;
        ushort* dst;
        int drow;
        if (row < 32)       { src = Wq + (size_t)row * CC;          s = SCALEF; dst = Wall; drow = row; }
        else if (row < 64)  { src = Wk + (size_t)(row - 32) * CC;   dst = Wall; drow = row; }
        else if (row < 320) { src = Wv + (size_t)(row - 64) * CC;   dst = Wall; drow = row; }
        else                { src = Wp + (size_t)(row - 320) * CC;  dst = Wpb;  drow = row - 320; }
        const floatx4 w = *(const floatx4*)(src + col);
        int2 d;
        d.x = pk_trunc(w[0] * s, w[1] * s);
        d.y = pk_trunc(w[2] * s, w[3] * s);
        *(int2*)(dst + (size_t)drow * CC + col) = d;
    }

    const int b = blockIdx.z;
    const int c0 = blockIdx.y * 64;
    const int n0 = blockIdx.x * 64;
    const int cl = (t >> 4) * 4;
    const int nl = (t & 15) * 4;

    const float* src = x + ((size_t)b * CC + c0 + cl) * NN + n0 + nl;
    floatx4 v[4];
    #pragma unroll
    for (int i = 0; i < 4; ++i) v[i] = *(const floatx4*)(src + (size_t)i * NN);

    #pragma unroll
    for (int j = 0; j < 4; ++j) {
        *(int*)&tile[(nl + j) * TP + cl]     = pk_trunc(v[0][j], v[1][j]);
        *(int*)&tile[(nl + j) * TP + cl + 2] = pk_trunc(v[2][j], v[3][j]);
    }
    __syncthreads();

    const int nr = t >> 2;
    const int coff = (t & 3) * 16;
    int r[8];
    #pragma unroll
    for (int u = 0; u < 8; ++u) r[u] = *(const int*)&tile[nr * TP + coff + u * 2];
    ushort* dst = xT + ((size_t)b * NN + n0 + nr) * CC + c0 + coff;
    intx4 o0 = {r[0], r[1], r[2], r[3]};
    intx4 o1 = {r[4], r[5], r[6], r[7]};
    *(intx4*)dst = o0;
    *(intx4*)(dst + 8) = o1;
}

// ---------------------------------------------------------------------------
// Kernel 1: MFMA QKV projection (R5-verbatim) — bf16 short8 loads, A from
// Wall, B from xT.
// ---------------------------------------------------------------------------
__global__ __launch_bounds__(256) void qkv_mfma(
    const ushort* __restrict__ xT, const ushort* __restrict__ Wall,
    const float* __restrict__ bq, const float* __restrict__ bk,
    const float* __restrict__ bv,
    ushort* __restrict__ qb, ushort* __restrict__ kb, ushort* __restrict__ vb)
{
    const int t = threadIdx.x;
    const int wave = t >> 6;
    const int lane = t & 63;
    const int l15 = lane & 15, qd = lane >> 4;
    const int b = blockIdx.z, mt = blockIdx.y;   // mt 0..9
    const int n0 = blockIdx.x * 128 + wave * 32;

    const ushort* arow = Wall + (size_t)(mt * 32 + l15) * CC + qd * 8;
    const ushort* brow = xT + ((size_t)b * NN + n0 + l15) * CC + qd * 8;

    floatx4 z = {0.f, 0.f, 0.f, 0.f};
    floatx4 acc[2][2];
    acc[0][0] = z; acc[0][1] = z; acc[1][0] = z; acc[1][1] = z;

    #pragma unroll
    for (int k0 = 0; k0 < CC; k0 += 32) {
        short8 af[2], bfr[2];
        af[0]  = *(const short8*)(arow + k0);
        af[1]  = *(const short8*)(arow + 16 * CC + k0);
        bfr[0] = *(const short8*)(brow + k0);
        bfr[1] = *(const short8*)(brow + 16 * CC + k0);
        #pragma unroll
        for (int fm = 0; fm < 2; ++fm)
            #pragma unroll
            for (int fn = 0; fn < 2; ++fn)
                acc[fm][fn] = __builtin_amdgcn_mfma_f32_16x16x32_bf16(af[fm], bfr[fn], acc[fm][fn], 0, 0, 0);
    }

    #pragma unroll
    for (int fm = 0; fm < 2; ++fm) {
        const int o0 = fm * 16 + qd * 4;
        if (mt == 0) {
            const floatx4 bb = *(const floatx4*)(bq + o0);
            #pragma unroll
            for (int fn = 0; fn < 2; ++fn) {
                ushort4 h;
                h.x = f2bf(acc[fm][fn][0] + bb[0] * SCALEF);
                h.y = f2bf(acc[fm][fn][1] + bb[1] * SCALEF);
                h.z = f2bf(acc[fm][fn][2] + bb[2] * SCALEF);
                h.w = f2bf(acc[fm][fn][3] + bb[3] * SCALEF);
                *(ushort4*)(qb + ((size_t)b * NN + n0 + fn * 16 + l15) * DD + o0) = h;
            }
        } else if (mt == 1) {
            const floatx4 bb = *(const floatx4*)(bk + o0);
            #pragma unroll
            for (int fn = 0; fn < 2; ++fn) {
                ushort4 h;
                h.x = f2bf(acc[fm][fn][0] + bb[0]);
                h.y = f2bf(acc[fm][fn][1] + bb[1]);
                h.z = f2bf(acc[fm][fn][2] + bb[2]);
                h.w = f2bf(acc[fm][fn][3] + bb[3]);
                *(ushort4*)(kb + ((size_t)b * NN + n0 + fn * 16 + l15) * DD + o0) = h;
            }
        } else {
            const int oc = (mt - 2) * 32 + o0;
            const floatx4 bb = *(const floatx4*)(bv + oc);
            #pragma unroll
            for (int r = 0; r < 4; ++r)
                #pragma unroll
                for (int fn = 0; fn < 2; ++fn)
                    vb[((size_t)b * CC + oc + r) * NN + n0 + fn * 16 + l15] = f2bf(acc[fm][fn][r] + bb[r]);
        }
    }
}

// ---------------------------------------------------------------------------
// Kernel 2: MFMA flash attention v8 — 32x32x16 shapes + permlane32_swap
// softmax transpose (NO LDS in the main loop).  Same macro-structure as R5:
// block = 4 key-quarter waves x (64 q x 128 c), grid (8,32,2), additive
// partial O/l, 3-barrier reduction tree at the end.
//   QK: s[qg] = mfma32(K_d0..15, Q) + mfma32(K_d16..31, Q):
//       col=lane&31=q, reg r -> key (r&3)+8*(r>>2)+4*hi  [HW-verified m74].
//   exp2 -> pk_trunc pairs -> 2x permlane32_swap per 16-key half yields the
//   PV B-frag dwords exactly (d0,d2 = swap(pk01,pk45); d1,d3 = swap(pk23,pk67)).
//   PV: acc[qg][cg] += mfma32(V[c 32][k 16], P[k 16][q 32]) x 2 k-halves.
//   l-sum: 15-add VALU tree per qg per kt (no AGPR cost), partner lanes
//   folded once after the loop via __shfl(lane^32).
// ---------------------------------------------------------------------------
__global__ __launch_bounds__(256, 2) void attn_mfma(
    const ushort* __restrict__ qb, const ushort* __restrict__ kb,
    const ushort* __restrict__ vb, ushort* __restrict__ aoT)
{
    __shared__ float red[2][8192];   // [slot][((qg*4+cg)*16 + r)*64 + lane]
    __shared__ float lred[2][64];    // [slot][qg*32 + (lane&31)]

    const int t = threadIdx.x;
    const int kh = t >> 6;               // key-quarter 0..3
    const int lane = t & 63;
    const int l31 = lane & 31;
    const bool hi = lane >= 32;
    const int hib = hi ? 8 : 0;
    const int slot = blockIdx.x;
    const int b = slot >> 1;
    const int qt = (slot & 1) * 32 + blockIdx.y;
    const int q0 = qt * 64;
    const int c0 = blockIdx.z * 128;

    // Q B-frags: B[d][q], col=lane&31=q, k=d=hi*8+j; qg = 32-q group, dh = d-half
    short8 qf[2][2];
    #pragma unroll
    for (int qg = 0; qg < 2; ++qg)
        #pragma unroll
        for (int dh = 0; dh < 2; ++dh)
            qf[qg][dh] = *(const short8*)(qb + ((size_t)b * NN + q0 + qg * 32 + l31) * DD + dh * 16 + hib);

    // K A-frag rows (key = lane&31 within each 32-key step), V A-frag rows (c = lane&31 + cg*32)
    const ushort* krow = kb + ((size_t)b * NN + kh * 1024 + l31) * DD + hib;
    const ushort* vrow = vb + ((size_t)b * CC + c0 + l31) * (size_t)NN + kh * 1024 + hib;

    floatx16 z16 = {0.f,0.f,0.f,0.f,0.f,0.f,0.f,0.f,0.f,0.f,0.f,0.f,0.f,0.f,0.f,0.f};
    floatx16 acc[2][4];   // [qg][cg]: 64q x 128c wave tile
    #pragma unroll
    for (int qg = 0; qg < 2; ++qg)
        #pragma unroll
        for (int cg = 0; cg < 4; ++cg) acc[qg][cg] = z16;
    float lsum[2] = {0.f, 0.f};

    for (int kt = 0; kt < 32; ++kt) {
        short8 kf0 = *(const short8*)(krow);        // d 0..15
        short8 kf1 = *(const short8*)(krow + 16);   // d 16..31
        krow += 32 * DD;
        short8 vf[4][2];
        #pragma unroll
        for (int cg = 0; cg < 4; ++cg)
            #pragma unroll
            for (int k2 = 0; k2 < 2; ++k2)
                vf[cg][k2] = *(const short8*)(vrow + (size_t)cg * 32 * NN + k2 * 16);
        vrow += 32;

        short8 ptB[2][2];   // [qg][k-half]: PV B-frags
        #pragma unroll
        for (int qg = 0; qg < 2; ++qg) {
            floatx16 s = __builtin_amdgcn_mfma_f32_32x32x16_bf16(kf0, qf[qg][0], z16, 0, 0, 0);
            s = __builtin_amdgcn_mfma_f32_32x32x16_bf16(kf1, qf[qg][1], s, 0, 0, 0);

            float e[16];
            #pragma unroll
            for (int r = 0; r < 16; ++r) e[r] = fast_exp2(s[r]);

            lsum[qg] += (((e[0]+e[1])+(e[2]+e[3]))+((e[4]+e[5])+(e[6]+e[7])))
                      + (((e[8]+e[9])+(e[10]+e[11]))+((e[12]+e[13])+(e[14]+e[15])));

            // keys 0-15 (B-frag k-half 0)
            int a0 = pk_trunc(e[0], e[1]),  b0 = pk_trunc(e[2], e[3]);
            int c0w = pk_trunc(e[4], e[5]), d0 = pk_trunc(e[6], e[7]);
            plswap(a0, c0w);   // a0 -> d0 slot, c0w -> d2 slot
            plswap(b0, d0);    // b0 -> d1 slot, d0 -> d3 slot
            intx4 f0 = {a0, b0, c0w, d0};
            ptB[qg][0] = __builtin_bit_cast(short8, f0);

            // keys 16-31 (B-frag k-half 1)
            int a1 = pk_trunc(e[8], e[9]),   b1 = pk_trunc(e[10], e[11]);
            int c1 = pk_trunc(e[12], e[13]), d1 = pk_trunc(e[14], e[15]);
            plswap(a1, c1);
            plswap(b1, d1);
            intx4 f1 = {a1, b1, c1, d1};
            ptB[qg][1] = __builtin_bit_cast(short8, f1);
        }

        __builtin_amdgcn_s_setprio(1);
        #pragma unroll
        for (int cg = 0; cg < 4; ++cg)
            #pragma unroll
            for (int qg = 0; qg < 2; ++qg) {
                acc[qg][cg] = __builtin_amdgcn_mfma_f32_32x32x16_bf16(vf[cg][0], ptB[qg][0], acc[qg][cg], 0, 0, 0);
                acc[qg][cg] = __builtin_amdgcn_mfma_f32_32x32x16_bf16(vf[cg][1], ptB[qg][1], acc[qg][cg], 0, 0, 0);
            }
        __builtin_amdgcn_s_setprio(0);
    }

    // fold partner-lane key-halves (each lane summed only its 16 of 32 keys)
    #pragma unroll
    for (int qg = 0; qg < 2; ++qg)
        lsum[qg] += __shfl(lsum[qg], lane ^ 32);

    // ---- reduction tree over key-quarters: (0+=1, 2+=3), then 0+=2 ----
    if (kh & 1) {
        const int s = kh >> 1;
        #pragma unroll
        for (int qg = 0; qg < 2; ++qg)
            #pragma unroll
            for (int cg = 0; cg < 4; ++cg)
                #pragma unroll
                for (int r = 0; r < 16; ++r)
                    red[s][((qg * 4 + cg) * 16 + r) * 64 + lane] = acc[qg][cg][r];
        if (!hi)
            #pragma unroll
            for (int qg = 0; qg < 2; ++qg) lred[s][qg * 32 + l31] = lsum[qg];
    }
    __syncthreads();
    if (!(kh & 1)) {
        const int s = kh >> 1;
        #pragma unroll
        for (int qg = 0; qg < 2; ++qg) {
            #pragma unroll
            for (int cg = 0; cg < 4; ++cg)
                #pragma unroll
                for (int r = 0; r < 16; ++r)
                    acc[qg][cg][r] += red[s][((qg * 4 + cg) * 16 + r) * 64 + lane];
            lsum[qg] += lred[s][qg * 32 + l31];
        }
    }
    __syncthreads();
    if (kh == 2) {
        #pragma unroll
        for (int qg = 0; qg < 2; ++qg)
            #pragma unroll
            for (int cg = 0; cg < 4; ++cg)
                #pragma unroll
                for (int r = 0; r < 16; ++r)
                    red[0][((qg * 4 + cg) * 16 + r) * 64 + lane] = acc[qg][cg][r];
        if (!hi)
            #pragma unroll
            for (int qg = 0; qg < 2; ++qg) lred[0][qg * 32 + l31] = lsum[qg];
    }
    __syncthreads();
    if (kh == 0) {
        #pragma unroll
        for (int qg = 0; qg < 2; ++qg) {
            #pragma unroll
            for (int cg = 0; cg < 4; ++cg)
                #pragma unroll
                for (int r = 0; r < 16; ++r)
                    acc[qg][cg][r] += red[0][((qg * 4 + cg) * 16 + r) * 64 + lane];
            lsum[qg] += lred[0][qg * 32 + l31];
        }
        // store: D layout col=lane&31=q, row c = (r&3)+8*(r>>2)+4*hi
        #pragma unroll
        for (int qg = 0; qg < 2; ++qg) {
            const float inv = 1.0f / lsum[qg];
            ushort* dst = aoT + ((size_t)b * NN + q0 + qg * 32 + l31) * CC + c0;
            #pragma unroll
            for (int cg = 0; cg < 4; ++cg) {
                #pragma unroll
                for (int rq = 0; rq < 4; ++rq) {
                    ushort4 h;
                    h.x = f2bf(acc[qg][cg][rq * 4 + 0] * inv);
                    h.y = f2bf(acc[qg][cg][rq * 4 + 1] * inv);
                    h.z = f2bf(acc[qg][cg][rq * 4 + 2] * inv);
                    h.w = f2bf(acc[qg][cg][rq * 4 + 3] * inv);
                    *(ushort4*)(dst + cg * 32 + rq * 8 + (hi ? 4 : 0)) = h;
                }
            }
        }
    }
}

// ---------------------------------------------------------------------------
// Kernel 3: MFMA output projection + residual (R5-verbatim, Wpb path).
// ---------------------------------------------------------------------------
__global__ __launch_bounds__(256) void proj_mfma(
    const ushort* __restrict__ aoT, const ushort* __restrict__ Wpb,
    const float* __restrict__ bp, const float* __restrict__ x,
    const float* __restrict__ gamma, float* __restrict__ out)
{
    const int t = threadIdx.x;
    const int wave = t >> 6;
    const int lane = t & 63;
    const int l15 = lane & 15;
    const int qd = lane >> 4;
    const int b = blockIdx.z;
    const int m0 = blockIdx.y * 32;
    const int n0 = blockIdx.x * 128 + wave * 32;

    floatx4 z = {0.f, 0.f, 0.f, 0.f};
    floatx4 acc[2][2];
    acc[0][0] = z; acc[0][1] = z; acc[1][0] = z; acc[1][1] = z;

    const ushort* arow = aoT + ((size_t)b * NN + n0 + l15) * CC + qd * 8;
    const ushort* wrow = Wpb + (size_t)(m0 + l15) * CC + qd * 8;

    #pragma unroll
    for (int k0 = 0; k0 < CC; k0 += 32) {
        short8 af[2], bfr[2];
        af[0]  = *(const short8*)(wrow + k0);
        af[1]  = *(const short8*)(wrow + 16 * CC + k0);
        bfr[0] = *(const short8*)(arow + k0);
        bfr[1] = *(const short8*)(arow + 16 * CC + k0);
        #pragma unroll
        for (int fm = 0; fm < 2; ++fm)
            #pragma unroll
            for (int fn = 0; fn < 2; ++fn)
                acc[fm][fn] = __builtin_amdgcn_mfma_f32_16x16x32_bf16(af[fm], bfr[fn], acc[fm][fn], 0, 0, 0);
    }

    const float g = gamma[0];
    #pragma unroll
    for (int fm = 0; fm < 2; ++fm) {
        #pragma unroll
        for (int r = 0; r < 4; ++r) {
            int m = m0 + fm * 16 + qd * 4 + r;
            float bpv = bp[m];
            #pragma unroll
            for (int fn = 0; fn < 2; ++fn) {
                size_t addr = ((size_t)b * CC + m) * NN + n0 + fn * 16 + l15;
                out[addr] = fmaf(g, acc[fm][fn][r] + bpv, x[addr]);
            }
        }
    }
}

extern "C" void kernel_launch(void* const* d_in, const int* in_sizes, int n_in,
                              void* d_out, int out_size, void* d_ws, size_t ws_size,
                              hipStream_t stream)
{
    const float* x     = (const float*)d_in[0];
    const float* Wq    = (const float*)d_in[1];
    const float* bq    = (const float*)d_in[2];
    const float* Wk    = (const float*)d_in[3];
    const float* bk    = (const float*)d_in[4];
    const float* Wv    = (const float*)d_in[5];
    const float* bv    = (const float*)d_in[6];
    const float* Wp    = (const float*)d_in[7];
    const float* bp    = (const float*)d_in[8];
    const float* gamma = (const float*)d_in[9];
    float* out = (float*)d_out;

    ushort* qbw  = (ushort*)d_ws;                        // B*N*32  bf16 = 1 MB
    ushort* kbw  = qbw + (size_t)BB * NN * DD;           // B*N*32  bf16 = 1 MB
    ushort* vbw  = kbw + (size_t)BB * NN * DD;           // B*C*N   bf16 = 8 MB
    ushort* xaoT = vbw + (size_t)BB * CC * NN;           // xT during qkv, aoT after attn (8 MB, aliased)
    ushort* Wall = xaoT + (size_t)BB * NN * CC;          // 320*256 bf16 = 160 KB
    ushort* Wpb  = Wall + (size_t)320 * CC;              // 256*256 bf16 = 128 KB

    prep_fused<<<dim3(NN / 64, CC / 64, BB), 256, 0, stream>>>(x, Wq, Wk, Wv, Wp, xaoT, Wall, Wpb);
    qkv_mfma<<<dim3(NN / 128, 10, BB), 256, 0, stream>>>(xaoT, Wall, bq, bk, bv, qbw, kbw, vbw);
    attn_mfma<<<dim3(8, 32, 2), 256, 0, stream>>>(qbw, kbw, vbw, xaoT);
    proj_mfma<<<dim3(NN / 128, CC / 32, BB), 256, 0, stream>>>(xaoT, Wpb, bp, x, gamma, out);
}